// Round 9
// baseline (1272.747 us; speedup 1.0000x reference)
//
#include <hip/hip_runtime.h>

constexpr int N = 100000;
constexpr int E = 1600000;
constexpr int NB = (N + 511) / 512;     // 196 dst-buckets of 512 nodes

using bf16x8 = __attribute__((ext_vector_type(8))) short;
using f32x4  = __attribute__((ext_vector_type(4))) float;

__device__ inline unsigned short f2bf(float x) {
    unsigned int b = __builtin_bit_cast(unsigned int, x);
    b = (b + 0x7FFFu + ((b >> 16) & 1u)) >> 16;
    return (unsigned short)b;
}
__device__ inline float bf2f(unsigned int u) {
    unsigned int b = u << 16;
    return __builtin_bit_cast(float, b);
}

// ================= bucketed CSR build =================
// Pass A: per-block LDS histogram of dst>>9 -> global bcnt (196 counters).
__global__ __launch_bounds__(256) void bucket_hist(const int* __restrict__ ei,
                                                   int* __restrict__ bcnt) {
    __shared__ int h[NB];
    for (int i = threadIdx.x; i < NB; i += 256) h[i] = 0;
    __syncthreads();
    for (int e = blockIdx.x * 256 + threadIdx.x; e < E; e += gridDim.x * 256)
        atomicAdd(&h[ei[E + e] >> 9], 1);
    __syncthreads();
    for (int i = threadIdx.x; i < NB; i += 256)
        if (h[i]) atomicAdd(&bcnt[i], h[i]);
}

// Pass B: exclusive scan of 196 bucket counts (one block).
__global__ void bucket_scan(const int* __restrict__ bcnt,
                            int* __restrict__ boff, int* __restrict__ bcur) {
    __shared__ int tmp[256];
    int t = threadIdx.x;
    int v = (t < NB) ? bcnt[t] : 0;
    tmp[t] = v;
    __syncthreads();
    for (int d = 1; d < 256; d <<= 1) {
        int u = (t >= d) ? tmp[t - d] : 0;
        __syncthreads();
        tmp[t] += u;
        __syncthreads();
    }
    if (t < NB) { int o = tmp[t] - v; boff[t] = o; bcur[t] = o; }
    if (t == 0) boff[NB] = E;
}

// Pass C: scatter packed (src<<9 | dst&511) into bucket-contiguous regions.
// Cursor grants are sequential per bucket -> L2 write-coalesces lines.
__global__ __launch_bounds__(256) void bucket_scatter(const int* __restrict__ ei,
                                                      int* __restrict__ bcur,
                                                      int* __restrict__ pairs) {
    for (int e = blockIdx.x * 256 + threadIdx.x; e < E; e += gridDim.x * 256) {
        int s = ei[e], d = ei[E + e];
        int pos = atomicAdd(&bcur[d >> 9], 1);
        pairs[pos] = (s << 9) | (d & 511);
    }
}

// Pass D: one block per bucket: local hist+scan+scatter in LDS, coalesced csr
// write, and off[] emission. Bucket base in pairs == base in csr (dst-ordered).
__global__ __launch_bounds__(256) void bucket_csr(const int* __restrict__ pairs,
                                                  const int* __restrict__ boff,
                                                  int* __restrict__ csr,
                                                  int* __restrict__ off) {
    constexpr int CAP = 12288;   // mean bucket 8192, +45 sigma margin
    __shared__ int lcsr[CAP];
    __shared__ int lh[512], lo[512], lc[512], st[256];
    const int b = blockIdx.x;
    const int base = boff[b];
    const int cnt  = boff[b + 1] - base;
    const int t = threadIdx.x;
    lh[t] = 0; lh[t + 256] = 0;
    __syncthreads();
    for (int i = t; i < cnt; i += 256)
        atomicAdd(&lh[pairs[base + i] & 511], 1);
    __syncthreads();
    int a0 = lh[2 * t], a1 = lh[2 * t + 1];
    int ps = a0 + a1;
    st[t] = ps;
    __syncthreads();
    for (int d = 1; d < 256; d <<= 1) {
        int u = (t >= d) ? st[t - d] : 0;
        __syncthreads();
        st[t] += u;
        __syncthreads();
    }
    int excl = st[t] - ps;
    lo[2 * t] = excl;      lo[2 * t + 1] = excl + a0;
    lc[2 * t] = excl;      lc[2 * t + 1] = excl + a0;
    __syncthreads();
    #pragma unroll
    for (int l = t; l < 512; l += 256) {
        int node = b * 512 + l;
        if (node < N) off[node] = base + lo[l];
    }
    for (int i = t; i < cnt; i += 256) {
        int v = pairs[base + i];
        int pos = atomicAdd(&lc[v & 511], 1);
        if (pos < CAP) lcsr[pos] = v >> 9;
        else           csr[base + pos] = v >> 9;   // safety, never expected
    }
    __syncthreads();
    int lim = cnt < CAP ? cnt : CAP;
    for (int i = t; i < lim; i += 256) csr[base + i] = lcsr[i];
}

// ================= fp32 -> bf16 converts =================
__global__ __launch_bounds__(256) void conv_x8(const float* __restrict__ in,
                                               unsigned short* __restrict__ out,
                                               int n8) {
    int i = blockIdx.x * 256 + threadIdx.x;
    if (i >= n8) return;
    const float* p = in + (size_t)i * 8;
    float4 v0 = *(const float4*)p;
    float4 v1 = *(const float4*)(p + 4);
    uint4 o;
    o.x = (unsigned)f2bf(v0.x) | ((unsigned)f2bf(v0.y) << 16);
    o.y = (unsigned)f2bf(v0.z) | ((unsigned)f2bf(v0.w) << 16);
    o.z = (unsigned)f2bf(v1.x) | ((unsigned)f2bf(v1.y) << 16);
    o.w = (unsigned)f2bf(v1.z) | ((unsigned)f2bf(v1.w) << 16);
    *(uint4*)(out + (size_t)i * 8) = o;
}

struct WC {
    const float* s[12];
    unsigned short* d[12];
    int n[12];
};
__global__ __launch_bounds__(256) void conv_w(WC wc) {
    int mi = blockIdx.y;
    const float* s = wc.s[mi];
    unsigned short* d = wc.d[mi];
    int n = wc.n[mi];
    for (int i = blockIdx.x * 256 + threadIdx.x; i < n; i += gridDim.x * 256)
        d[i] = f2bf(s[i]);
}

// ================= pull aggregation over bf16 messages =================
// MODE 0: write bf16 agg only. MODE 1: fp32 add into outf. MODE 2: both.
template<int C, int MODE>
__global__ __launch_bounds__(256) void pull_bf(const unsigned short* __restrict__ feat,
                                               const int* __restrict__ off,
                                               const int* __restrict__ csr,
                                               float* __restrict__ outf,
                                               unsigned short* __restrict__ outb) {
    constexpr int TPN = C / 8;
    int t = blockIdx.x * 256 + threadIdx.x;
    int n = t / TPN, g = t % TPN;
    if (n >= N) return;
    int beg = off[n];
    int end = (n == N - 1) ? E : off[n + 1];
    float a[8];
    #pragma unroll
    for (int i = 0; i < 8; ++i) a[i] = 0.f;
    for (int j = beg; j < end; ++j) {
        int s = csr[j];
        uint4 v = *(const uint4*)(feat + (size_t)s * C + g * 8);
        a[0] += bf2f(v.x & 0xFFFFu); a[1] += bf2f(v.x >> 16);
        a[2] += bf2f(v.y & 0xFFFFu); a[3] += bf2f(v.y >> 16);
        a[4] += bf2f(v.z & 0xFFFFu); a[5] += bf2f(v.z >> 16);
        a[6] += bf2f(v.w & 0xFFFFu); a[7] += bf2f(v.w >> 16);
    }
    if (MODE >= 1) {
        float* op = outf + (size_t)n * C + g * 8;
        float4 b0 = *(const float4*)op, b1 = *(const float4*)(op + 4);
        a[0] += b0.x; a[1] += b0.y; a[2] += b0.z; a[3] += b0.w;
        a[4] += b1.x; a[5] += b1.y; a[6] += b1.z; a[7] += b1.w;
        *(float4*)op       = make_float4(a[0], a[1], a[2], a[3]);
        *(float4*)(op + 4) = make_float4(a[4], a[5], a[6], a[7]);
    }
    if (MODE != 1) {
        uint4 o;
        o.x = (unsigned)f2bf(a[0]) | ((unsigned)f2bf(a[1]) << 16);
        o.y = (unsigned)f2bf(a[2]) | ((unsigned)f2bf(a[3]) << 16);
        o.z = (unsigned)f2bf(a[4]) | ((unsigned)f2bf(a[5]) << 16);
        o.w = (unsigned)f2bf(a[6]) | ((unsigned)f2bf(a[7]) << 16);
        *(uint4*)(outb + (size_t)n * C + g * 8) = o;
    }
}

// ================= MFMA bf16 GEMM =================
// out[row][0..M) = act( in1[row]@W1^T (+ in2[row]@W2^T) + bias ), bf16 in,
// fp32 accumulate. Block = 4 waves = 64 rows. Fragments (m89/m97-verified):
// A/B: lane&15 = row/col, k = (lane>>4)*8 + j; C/D: col=lane&15, row=(lane>>4)*4+reg.
template<int K1, int K2, int M, bool RELU, bool OBF>
__global__ __launch_bounds__(256) void gemm_mfma(
    const unsigned short* __restrict__ in1, const unsigned short* __restrict__ W1,
    const unsigned short* __restrict__ in2, const unsigned short* __restrict__ W2,
    const float* __restrict__ bias, void* __restrict__ outv)
{
    constexpr int KV = K1 + K2;
    constexpr int SK = KV + 8;
    constexpr int NF = M / 16;
    __shared__ unsigned short As[64 * SK];
    __shared__ unsigned short Bs[M * SK];

    const int tid = threadIdx.x;
    const int row0 = blockIdx.x * 64;

    constexpr int AV = 64 * (KV / 8);
    for (int idx = tid; idx < AV; idx += 256) {
        int r = idx / (KV / 8), c = (idx % (KV / 8)) * 8;
        int rr = row0 + r;
        uint4 v = {0u, 0u, 0u, 0u};
        if (rr < N) {
            if constexpr (K2 == 0) {
                v = *(const uint4*)(in1 + (size_t)rr * K1 + c);
            } else {
                v = (c < K1) ? *(const uint4*)(in1 + (size_t)rr * K1 + c)
                             : *(const uint4*)(in2 + (size_t)rr * K2 + (c - K1));
            }
        }
        *(uint4*)&As[r * SK + c] = v;
    }
    constexpr int BV = M * (KV / 8);
    for (int idx = tid; idx < BV; idx += 256) {
        int m = idx / (KV / 8), c = (idx % (KV / 8)) * 8;
        uint4 v;
        if constexpr (K2 == 0) {
            v = *(const uint4*)(W1 + (size_t)m * K1 + c);
        } else {
            v = (c < K1) ? *(const uint4*)(W1 + (size_t)m * K1 + c)
                         : *(const uint4*)(W2 + (size_t)m * K2 + (c - K1));
        }
        *(uint4*)&Bs[m * SK + c] = v;
    }
    __syncthreads();

    const int lane = tid & 63;
    const int wv   = tid >> 6;
    const int lrow = lane & 15;
    const int kg   = lane >> 4;

    f32x4 acc[NF];
    #pragma unroll
    for (int cf = 0; cf < NF; ++cf) acc[cf] = (f32x4){0.f, 0.f, 0.f, 0.f};

    #pragma unroll
    for (int k0 = 0; k0 < KV; k0 += 32) {
        bf16x8 a = *(const bf16x8*)&As[(wv * 16 + lrow) * SK + k0 + kg * 8];
        #pragma unroll
        for (int cf = 0; cf < NF; ++cf) {
            bf16x8 b = *(const bf16x8*)&Bs[(cf * 16 + lrow) * SK + k0 + kg * 8];
            acc[cf] = __builtin_amdgcn_mfma_f32_16x16x32_bf16(a, b, acc[cf], 0, 0, 0);
        }
    }

    #pragma unroll
    for (int cf = 0; cf < NF; ++cf) {
        int col = cf * 16 + lrow;
        float bsv = bias ? bias[col] : 0.f;
        #pragma unroll
        for (int r = 0; r < 4; ++r) {
            int row = row0 + wv * 16 + kg * 4 + r;
            if (row < N) {
                float v = acc[cf][r] + bsv;
                if (RELU) v = fmaxf(v, 0.f);
                if constexpr (OBF)
                    ((unsigned short*)outv)[(size_t)row * M + col] = f2bf(v);
                else
                    ((float*)outv)[(size_t)row * M + col] = v;
            }
        }
    }
}

extern "C" void kernel_launch(void* const* d_in, const int* in_sizes, int n_in,
                              void* d_out, int out_size, void* d_ws, size_t ws_size,
                              hipStream_t stream)
{
    const float* x   = (const float*)d_in[0];
    const int*   ei  = (const int*)d_in[1];
    const float *e1_Wp=(const float*)d_in[2],  *e1_bp=(const float*)d_in[3],
                *e1_Wl=(const float*)d_in[4],  *e1_bl=(const float*)d_in[5],
                *e1_Wr=(const float*)d_in[6];
    const float *e2_Wp=(const float*)d_in[7],  *e2_bp=(const float*)d_in[8],
                *e2_Wl=(const float*)d_in[9],  *e2_bl=(const float*)d_in[10],
                *e2_Wr=(const float*)d_in[11];
    const float *d1_Wp=(const float*)d_in[12], *d1_bp=(const float*)d_in[13],
                *d1_Wl=(const float*)d_in[14], *d1_bl=(const float*)d_in[15],
                *d1_Wr=(const float*)d_in[16];
    const float *d2_Wp=(const float*)d_in[17], *d2_bp=(const float*)d_in[18],
                *d2_Wl=(const float*)d_in[19], *d2_bl=(const float*)d_in[20],
                *d2_Wr=(const float*)d_in[21];

    typedef unsigned short u16;

    // ---- workspace ----
    int* off  = (int*)d_ws;                       // N
    int* csr  = off + N;                          // E
    u16* xbf  = (u16*)(csr + E);                  // [N][64]
    u16* R1bf = xbf  + (size_t)N * 64;            // [N][128]
    u16* Hbf  = R1bf + (size_t)N * 128;           // [N][128] scratch
    u16* MSG  = Hbf  + (size_t)N * 128;           // [N][64]
    u16* AGG  = MSG  + (size_t)N * 64;            // [N][64]
    u16* zbf  = AGG  + (size_t)N * 64;            // [N][32]
    u16* WB   = zbf  + (size_t)N * 32;            // bf16 weights (87040 u16)
    int* bcnt = (int*)(WB + 87040);               // NB
    int* boff = bcnt + NB;                        // NB+1
    int* bcur = boff + NB + 1;                    // NB
    int* pairs = (int*)Hbf;   // E ints, aliases Hbf (CSR build precedes Hbf use)

    u16* b_e1Wp = WB;
    u16* b_e1Wl = b_e1Wp + 4096;
    u16* b_e1Wr = b_e1Wl + 8192;
    u16* b_e2Wr = b_e1Wr + 8192;
    u16* b_e2Wp = b_e2Wr + 4096;
    u16* b_e2Wl = b_e2Wp + 16384;
    u16* b_d1Wp = b_e2Wl + 4096;
    u16* b_d1Wl = b_d1Wp + 1024;
    u16* b_d1Wr = b_d1Wl + 4096;
    u16* b_d2Wr = b_d1Wr + 4096;
    u16* b_d2Wp = b_d2Wr + 8192;
    u16* b_d2Wl = b_d2Wp + 16384;

    float* xrec = (float*)d_out;                  // [N][64]
    float* z    = xrec + (size_t)N * 64;          // [N][32]

    const int GM = (N + 63) / 64;                 // 1563

    // ---- converts ----
    conv_x8<<<(N * 64 / 8 + 255) / 256, 256, 0, stream>>>(x, xbf, N * 64 / 8);
    WC wc;
    const float* ws_[12] = {e1_Wp, e1_Wl, e1_Wr, e2_Wr, e2_Wp, e2_Wl,
                            d1_Wp, d1_Wl, d1_Wr, d2_Wr, d2_Wp, d2_Wl};
    u16* wd_[12] = {b_e1Wp, b_e1Wl, b_e1Wr, b_e2Wr, b_e2Wp, b_e2Wl,
                    b_d1Wp, b_d1Wl, b_d1Wr, b_d2Wr, b_d2Wp, b_d2Wl};
    int wn_[12] = {4096, 8192, 8192, 4096, 16384, 4096,
                   1024, 4096, 4096, 8192, 16384, 8192};
    for (int i = 0; i < 12; ++i) { wc.s[i] = ws_[i]; wc.d[i] = wd_[i]; wc.n[i] = wn_[i]; }
    conv_w<<<dim3(64, 12), 256, 0, stream>>>(wc);

    // ---- bucketed CSR build ----
    hipMemsetAsync(bcnt, 0, NB * sizeof(int), stream);
    bucket_hist<<<2048, 256, 0, stream>>>(ei, bcnt);
    bucket_scan<<<1, 256, 0, stream>>>(bcnt, boff, bcur);
    bucket_scatter<<<2048, 256, 0, stream>>>(ei, bcur, pairs);
    bucket_csr<<<NB, 256, 0, stream>>>(pairs, boff, csr, off);

    // ---- conv1 (e1): 64 -> 128, relu ----
    gemm_mfma<64,0,64,true,true><<<GM, 256, 0, stream>>>(xbf, b_e1Wp, nullptr, nullptr, e1_bp, MSG);
    pull_bf<64,0><<<(N*8 + 255)/256, 256, 0, stream>>>(MSG, off, csr, nullptr, AGG);
    gemm_mfma<64,64,128,true,true><<<GM, 256, 0, stream>>>(AGG, b_e1Wl, xbf, b_e1Wr, e1_bl, R1bf);

    // ---- conv2 (e2): 128 -> 32 = z ----
    gemm_mfma<128,0,32,false,false><<<GM, 256, 0, stream>>>(R1bf, b_e2Wr, nullptr, nullptr, e2_bl, z);
    gemm_mfma<128,0,128,true,true><<<GM, 256, 0, stream>>>(R1bf, b_e2Wp, nullptr, nullptr, e2_bp, Hbf);
    gemm_mfma<128,0,32,false,true><<<GM, 256, 0, stream>>>(Hbf, b_e2Wl, nullptr, nullptr, nullptr, MSG);
    pull_bf<32,2><<<(N*4 + 255)/256, 256, 0, stream>>>(MSG, off, csr, z, zbf);

    // ---- conv3 (d1): 32 -> 128, relu ----
    gemm_mfma<32,0,32,true,true><<<GM, 256, 0, stream>>>(zbf, b_d1Wp, nullptr, nullptr, d1_bp, MSG);
    pull_bf<32,0><<<(N*4 + 255)/256, 256, 0, stream>>>(MSG, off, csr, nullptr, AGG);
    gemm_mfma<32,32,128,true,true><<<GM, 256, 0, stream>>>(AGG, b_d1Wl, zbf, b_d1Wr, d1_bl, R1bf);

    // ---- conv4 (d2): 128 -> 64 = x_rec ----
    gemm_mfma<128,0,64,false,false><<<GM, 256, 0, stream>>>(R1bf, b_d2Wr, nullptr, nullptr, d2_bl, xrec);
    gemm_mfma<128,0,128,true,true><<<GM, 256, 0, stream>>>(R1bf, b_d2Wp, nullptr, nullptr, d2_bp, Hbf);
    gemm_mfma<128,0,64,false,true><<<GM, 256, 0, stream>>>(Hbf, b_d2Wl, nullptr, nullptr, nullptr, MSG);
    pull_bf<64,1><<<(N*8 + 255)/256, 256, 0, stream>>>(MSG, off, csr, xrec, nullptr);
}

// Round 10
// 373.652 us; speedup vs baseline: 3.4062x; 3.4062x over previous
//
#include <hip/hip_runtime.h>

constexpr int N = 100000;
constexpr int E = 1600000;
constexpr int NB = (N + 511) / 512;     // 196 dst-buckets of 512 nodes

using bf16x8 = __attribute__((ext_vector_type(8))) short;
using f32x4  = __attribute__((ext_vector_type(4))) float;

__device__ inline unsigned short f2bf(float x) {
    unsigned int b = __builtin_bit_cast(unsigned int, x);
    b = (b + 0x7FFFu + ((b >> 16) & 1u)) >> 16;
    return (unsigned short)b;
}
__device__ inline float bf2f(unsigned int u) {
    unsigned int b = u << 16;
    return __builtin_bit_cast(float, b);
}

// ================= bucketed CSR build =================
// Pass A: per-block LDS histogram of dst>>9; ONE global atomic per
// (block,bucket). 256 blocks -> 50K global atomics total (~256/counter).
__global__ __launch_bounds__(256) void bucket_hist(const int* __restrict__ ei,
                                                   int* __restrict__ bcnt) {
    __shared__ int h[NB];
    for (int i = threadIdx.x; i < NB; i += 256) h[i] = 0;
    __syncthreads();
    for (int e = blockIdx.x * 256 + threadIdx.x; e < E; e += gridDim.x * 256)
        atomicAdd(&h[ei[E + e] >> 9], 1);
    __syncthreads();
    for (int i = threadIdx.x; i < NB; i += 256)
        if (h[i]) atomicAdd(&bcnt[i], h[i]);
}

// Pass B: exclusive scan of 196 bucket counts (one block).
__global__ void bucket_scan(const int* __restrict__ bcnt,
                            int* __restrict__ boff, int* __restrict__ bcur) {
    __shared__ int tmp[256];
    int t = threadIdx.x;
    int v = (t < NB) ? bcnt[t] : 0;
    tmp[t] = v;
    __syncthreads();
    for (int d = 1; d < 256; d <<= 1) {
        int u = (t >= d) ? tmp[t - d] : 0;
        __syncthreads();
        tmp[t] += u;
        __syncthreads();
    }
    if (t < NB) { int o = tmp[t] - v; boff[t] = o; bcur[t] = o; }
    if (t == 0) boff[NB] = E;
}

// Pass C: block-aggregated scatter. Each block owns a contiguous edge span:
// LDS hist -> one global atomicAdd per (block,bucket) reserves a range ->
// LDS cursors assign local ranks -> coalesced-ish packed writes.
__global__ __launch_bounds__(256) void bucket_scatter(const int* __restrict__ ei,
                                                      int* __restrict__ bcur,
                                                      int* __restrict__ pairs) {
    __shared__ int lh[NB], lbase[NB], lcur[NB];
    const int per = (E + gridDim.x - 1) / gridDim.x;
    const int beg = blockIdx.x * per;
    const int end = min(E, beg + per);
    for (int i = threadIdx.x; i < NB; i += 256) { lh[i] = 0; lcur[i] = 0; }
    __syncthreads();
    for (int e = beg + threadIdx.x; e < end; e += 256)
        atomicAdd(&lh[ei[E + e] >> 9], 1);
    __syncthreads();
    for (int i = threadIdx.x; i < NB; i += 256)
        lbase[i] = lh[i] ? atomicAdd(&bcur[i], lh[i]) : 0;
    __syncthreads();
    for (int e = beg + threadIdx.x; e < end; e += 256) {
        int s = ei[e], d = ei[E + e];
        int b = d >> 9;
        int r = atomicAdd(&lcur[b], 1);
        pairs[lbase[b] + r] = (s << 9) | (d & 511);
    }
}

// Pass D: one block per bucket: local hist+scan+scatter in LDS, coalesced csr
// write, and off[] emission. Bucket base in pairs == base in csr (dst-ordered).
__global__ __launch_bounds__(256) void bucket_csr(const int* __restrict__ pairs,
                                                  const int* __restrict__ boff,
                                                  int* __restrict__ csr,
                                                  int* __restrict__ off) {
    constexpr int CAP = 12288;   // mean bucket 8192, huge sigma margin
    __shared__ int lcsr[CAP];
    __shared__ int lh[512], lo[512], lc[512], st[256];
    const int b = blockIdx.x;
    const int base = boff[b];
    const int cnt  = boff[b + 1] - base;
    const int t = threadIdx.x;
    lh[t] = 0; lh[t + 256] = 0;
    __syncthreads();
    for (int i = t; i < cnt; i += 256)
        atomicAdd(&lh[pairs[base + i] & 511], 1);
    __syncthreads();
    int a0 = lh[2 * t], a1 = lh[2 * t + 1];
    int ps = a0 + a1;
    st[t] = ps;
    __syncthreads();
    for (int d = 1; d < 256; d <<= 1) {
        int u = (t >= d) ? st[t - d] : 0;
        __syncthreads();
        st[t] += u;
        __syncthreads();
    }
    int excl = st[t] - ps;
    lo[2 * t] = excl;      lo[2 * t + 1] = excl + a0;
    lc[2 * t] = excl;      lc[2 * t + 1] = excl + a0;
    __syncthreads();
    #pragma unroll
    for (int l = t; l < 512; l += 256) {
        int node = b * 512 + l;
        if (node < N) off[node] = base + lo[l];
    }
    for (int i = t; i < cnt; i += 256) {
        int v = pairs[base + i];
        int pos = atomicAdd(&lc[v & 511], 1);
        if (pos < CAP) lcsr[pos] = v >> 9;
        else           csr[base + pos] = v >> 9;   // safety, never expected
    }
    __syncthreads();
    int lim = cnt < CAP ? cnt : CAP;
    for (int i = t; i < lim; i += 256) csr[base + i] = lcsr[i];
}

// ================= fp32 -> bf16 converts =================
__global__ __launch_bounds__(256) void conv_x8(const float* __restrict__ in,
                                               unsigned short* __restrict__ out,
                                               int n8) {
    int i = blockIdx.x * 256 + threadIdx.x;
    if (i >= n8) return;
    const float* p = in + (size_t)i * 8;
    float4 v0 = *(const float4*)p;
    float4 v1 = *(const float4*)(p + 4);
    uint4 o;
    o.x = (unsigned)f2bf(v0.x) | ((unsigned)f2bf(v0.y) << 16);
    o.y = (unsigned)f2bf(v0.z) | ((unsigned)f2bf(v0.w) << 16);
    o.z = (unsigned)f2bf(v1.x) | ((unsigned)f2bf(v1.y) << 16);
    o.w = (unsigned)f2bf(v1.z) | ((unsigned)f2bf(v1.w) << 16);
    *(uint4*)(out + (size_t)i * 8) = o;
}

struct WC {
    const float* s[12];
    unsigned short* d[12];
    int n[12];
};
__global__ __launch_bounds__(256) void conv_w(WC wc) {
    int mi = blockIdx.y;
    const float* s = wc.s[mi];
    unsigned short* d = wc.d[mi];
    int n = wc.n[mi];
    for (int i = blockIdx.x * 256 + threadIdx.x; i < n; i += gridDim.x * 256)
        d[i] = f2bf(s[i]);
}

// ================= pull aggregation over bf16 messages =================
// MODE 0: write bf16 agg only. MODE 1: fp32 add into outf. MODE 2: both.
template<int C, int MODE>
__global__ __launch_bounds__(256) void pull_bf(const unsigned short* __restrict__ feat,
                                               const int* __restrict__ off,
                                               const int* __restrict__ csr,
                                               float* __restrict__ outf,
                                               unsigned short* __restrict__ outb) {
    constexpr int TPN = C / 8;
    int t = blockIdx.x * 256 + threadIdx.x;
    int n = t / TPN, g = t % TPN;
    if (n >= N) return;
    int beg = off[n];
    int end = (n == N - 1) ? E : off[n + 1];
    float a[8];
    #pragma unroll
    for (int i = 0; i < 8; ++i) a[i] = 0.f;
    for (int j = beg; j < end; ++j) {
        int s = csr[j];
        uint4 v = *(const uint4*)(feat + (size_t)s * C + g * 8);
        a[0] += bf2f(v.x & 0xFFFFu); a[1] += bf2f(v.x >> 16);
        a[2] += bf2f(v.y & 0xFFFFu); a[3] += bf2f(v.y >> 16);
        a[4] += bf2f(v.z & 0xFFFFu); a[5] += bf2f(v.z >> 16);
        a[6] += bf2f(v.w & 0xFFFFu); a[7] += bf2f(v.w >> 16);
    }
    if (MODE >= 1) {
        float* op = outf + (size_t)n * C + g * 8;
        float4 b0 = *(const float4*)op, b1 = *(const float4*)(op + 4);
        a[0] += b0.x; a[1] += b0.y; a[2] += b0.z; a[3] += b0.w;
        a[4] += b1.x; a[5] += b1.y; a[6] += b1.z; a[7] += b1.w;
        *(float4*)op       = make_float4(a[0], a[1], a[2], a[3]);
        *(float4*)(op + 4) = make_float4(a[4], a[5], a[6], a[7]);
    }
    if (MODE != 1) {
        uint4 o;
        o.x = (unsigned)f2bf(a[0]) | ((unsigned)f2bf(a[1]) << 16);
        o.y = (unsigned)f2bf(a[2]) | ((unsigned)f2bf(a[3]) << 16);
        o.z = (unsigned)f2bf(a[4]) | ((unsigned)f2bf(a[5]) << 16);
        o.w = (unsigned)f2bf(a[6]) | ((unsigned)f2bf(a[7]) << 16);
        *(uint4*)(outb + (size_t)n * C + g * 8) = o;
    }
}

// ================= MFMA bf16 GEMM =================
// out[row][0..M) = act( in1[row]@W1^T (+ in2[row]@W2^T) + bias ), bf16 in,
// fp32 accumulate. Block = 4 waves = 64 rows. Fragments (m89/m97-verified):
// A/B: lane&15 = row/col, k = (lane>>4)*8 + j; C/D: col=lane&15, row=(lane>>4)*4+reg.
template<int K1, int K2, int M, bool RELU, bool OBF>
__global__ __launch_bounds__(256) void gemm_mfma(
    const unsigned short* __restrict__ in1, const unsigned short* __restrict__ W1,
    const unsigned short* __restrict__ in2, const unsigned short* __restrict__ W2,
    const float* __restrict__ bias, void* __restrict__ outv)
{
    constexpr int KV = K1 + K2;
    constexpr int SK = KV + 8;
    constexpr int NF = M / 16;
    __shared__ unsigned short As[64 * SK];
    __shared__ unsigned short Bs[M * SK];

    const int tid = threadIdx.x;
    const int row0 = blockIdx.x * 64;

    constexpr int AV = 64 * (KV / 8);
    for (int idx = tid; idx < AV; idx += 256) {
        int r = idx / (KV / 8), c = (idx % (KV / 8)) * 8;
        int rr = row0 + r;
        uint4 v = {0u, 0u, 0u, 0u};
        if (rr < N) {
            if constexpr (K2 == 0) {
                v = *(const uint4*)(in1 + (size_t)rr * K1 + c);
            } else {
                v = (c < K1) ? *(const uint4*)(in1 + (size_t)rr * K1 + c)
                             : *(const uint4*)(in2 + (size_t)rr * K2 + (c - K1));
            }
        }
        *(uint4*)&As[r * SK + c] = v;
    }
    constexpr int BV = M * (KV / 8);
    for (int idx = tid; idx < BV; idx += 256) {
        int m = idx / (KV / 8), c = (idx % (KV / 8)) * 8;
        uint4 v;
        if constexpr (K2 == 0) {
            v = *(const uint4*)(W1 + (size_t)m * K1 + c);
        } else {
            v = (c < K1) ? *(const uint4*)(W1 + (size_t)m * K1 + c)
                         : *(const uint4*)(W2 + (size_t)m * K2 + (c - K1));
        }
        *(uint4*)&Bs[m * SK + c] = v;
    }
    __syncthreads();

    const int lane = tid & 63;
    const int wv   = tid >> 6;
    const int lrow = lane & 15;
    const int kg   = lane >> 4;

    f32x4 acc[NF];
    #pragma unroll
    for (int cf = 0; cf < NF; ++cf) acc[cf] = (f32x4){0.f, 0.f, 0.f, 0.f};

    #pragma unroll
    for (int k0 = 0; k0 < KV; k0 += 32) {
        bf16x8 a = *(const bf16x8*)&As[(wv * 16 + lrow) * SK + k0 + kg * 8];
        #pragma unroll
        for (int cf = 0; cf < NF; ++cf) {
            bf16x8 b = *(const bf16x8*)&Bs[(cf * 16 + lrow) * SK + k0 + kg * 8];
            acc[cf] = __builtin_amdgcn_mfma_f32_16x16x32_bf16(a, b, acc[cf], 0, 0, 0);
        }
    }

    #pragma unroll
    for (int cf = 0; cf < NF; ++cf) {
        int col = cf * 16 + lrow;
        float bsv = bias ? bias[col] : 0.f;
        #pragma unroll
        for (int r = 0; r < 4; ++r) {
            int row = row0 + wv * 16 + kg * 4 + r;
            if (row < N) {
                float v = acc[cf][r] + bsv;
                if (RELU) v = fmaxf(v, 0.f);
                if constexpr (OBF)
                    ((unsigned short*)outv)[(size_t)row * M + col] = f2bf(v);
                else
                    ((float*)outv)[(size_t)row * M + col] = v;
            }
        }
    }
}

extern "C" void kernel_launch(void* const* d_in, const int* in_sizes, int n_in,
                              void* d_out, int out_size, void* d_ws, size_t ws_size,
                              hipStream_t stream)
{
    const float* x   = (const float*)d_in[0];
    const int*   ei  = (const int*)d_in[1];
    const float *e1_Wp=(const float*)d_in[2],  *e1_bp=(const float*)d_in[3],
                *e1_Wl=(const float*)d_in[4],  *e1_bl=(const float*)d_in[5],
                *e1_Wr=(const float*)d_in[6];
    const float *e2_Wp=(const float*)d_in[7],  *e2_bp=(const float*)d_in[8],
                *e2_Wl=(const float*)d_in[9],  *e2_bl=(const float*)d_in[10],
                *e2_Wr=(const float*)d_in[11];
    const float *d1_Wp=(const float*)d_in[12], *d1_bp=(const float*)d_in[13],
                *d1_Wl=(const float*)d_in[14], *d1_bl=(const float*)d_in[15],
                *d1_Wr=(const float*)d_in[16];
    const float *d2_Wp=(const float*)d_in[17], *d2_bp=(const float*)d_in[18],
                *d2_Wl=(const float*)d_in[19], *d2_bl=(const float*)d_in[20],
                *d2_Wr=(const float*)d_in[21];

    typedef unsigned short u16;

    // ---- workspace ----
    int* off  = (int*)d_ws;                       // N
    int* csr  = off + N;                          // E
    u16* xbf  = (u16*)(csr + E);                  // [N][64]
    u16* R1bf = xbf  + (size_t)N * 64;            // [N][128]
    u16* Hbf  = R1bf + (size_t)N * 128;           // [N][128] scratch
    u16* MSG  = Hbf  + (size_t)N * 128;           // [N][64]
    u16* AGG  = MSG  + (size_t)N * 64;            // [N][64]
    u16* zbf  = AGG  + (size_t)N * 64;            // [N][32]
    u16* WB   = zbf  + (size_t)N * 32;            // bf16 weights (87040 u16)
    int* bcnt = (int*)(WB + 87040);               // NB
    int* boff = bcnt + NB;                        // NB+1
    int* bcur = boff + NB + 1;                    // NB
    int* pairs = (int*)Hbf;   // E ints, aliases Hbf (CSR build precedes Hbf use)

    u16* b_e1Wp = WB;
    u16* b_e1Wl = b_e1Wp + 4096;
    u16* b_e1Wr = b_e1Wl + 8192;
    u16* b_e2Wr = b_e1Wr + 8192;
    u16* b_e2Wp = b_e2Wr + 4096;
    u16* b_e2Wl = b_e2Wp + 16384;
    u16* b_d1Wp = b_e2Wl + 4096;
    u16* b_d1Wl = b_d1Wp + 1024;
    u16* b_d1Wr = b_d1Wl + 4096;
    u16* b_d2Wr = b_d1Wr + 4096;
    u16* b_d2Wp = b_d2Wr + 8192;
    u16* b_d2Wl = b_d2Wp + 16384;

    float* xrec = (float*)d_out;                  // [N][64]
    float* z    = xrec + (size_t)N * 64;          // [N][32]

    const int GM = (N + 63) / 64;                 // 1563

    // ---- converts ----
    conv_x8<<<(N * 64 / 8 + 255) / 256, 256, 0, stream>>>(x, xbf, N * 64 / 8);
    WC wc;
    const float* ws_[12] = {e1_Wp, e1_Wl, e1_Wr, e2_Wr, e2_Wp, e2_Wl,
                            d1_Wp, d1_Wl, d1_Wr, d2_Wr, d2_Wp, d2_Wl};
    u16* wd_[12] = {b_e1Wp, b_e1Wl, b_e1Wr, b_e2Wr, b_e2Wp, b_e2Wl,
                    b_d1Wp, b_d1Wl, b_d1Wr, b_d2Wr, b_d2Wp, b_d2Wl};
    int wn_[12] = {4096, 8192, 8192, 4096, 16384, 4096,
                   1024, 4096, 4096, 8192, 16384, 8192};
    for (int i = 0; i < 12; ++i) { wc.s[i] = ws_[i]; wc.d[i] = wd_[i]; wc.n[i] = wn_[i]; }
    conv_w<<<dim3(64, 12), 256, 0, stream>>>(wc);

    // ---- bucketed CSR build (block-aggregated atomics) ----
    hipMemsetAsync(bcnt, 0, NB * sizeof(int), stream);
    bucket_hist<<<256, 256, 0, stream>>>(ei, bcnt);
    bucket_scan<<<1, 256, 0, stream>>>(bcnt, boff, bcur);
    bucket_scatter<<<256, 256, 0, stream>>>(ei, bcur, pairs);
    bucket_csr<<<NB, 256, 0, stream>>>(pairs, boff, csr, off);

    // ---- conv1 (e1): 64 -> 128, relu ----
    gemm_mfma<64,0,64,true,true><<<GM, 256, 0, stream>>>(xbf, b_e1Wp, nullptr, nullptr, e1_bp, MSG);
    pull_bf<64,0><<<(N*8 + 255)/256, 256, 0, stream>>>(MSG, off, csr, nullptr, AGG);
    gemm_mfma<64,64,128,true,true><<<GM, 256, 0, stream>>>(AGG, b_e1Wl, xbf, b_e1Wr, e1_bl, R1bf);

    // ---- conv2 (e2): 128 -> 32 = z ----
    gemm_mfma<128,0,32,false,false><<<GM, 256, 0, stream>>>(R1bf, b_e2Wr, nullptr, nullptr, e2_bl, z);
    gemm_mfma<128,0,128,true,true><<<GM, 256, 0, stream>>>(R1bf, b_e2Wp, nullptr, nullptr, e2_bp, Hbf);
    gemm_mfma<128,0,32,false,true><<<GM, 256, 0, stream>>>(Hbf, b_e2Wl, nullptr, nullptr, nullptr, MSG);
    pull_bf<32,2><<<(N*4 + 255)/256, 256, 0, stream>>>(MSG, off, csr, z, zbf);

    // ---- conv3 (d1): 32 -> 128, relu ----
    gemm_mfma<32,0,32,true,true><<<GM, 256, 0, stream>>>(zbf, b_d1Wp, nullptr, nullptr, d1_bp, MSG);
    pull_bf<32,0><<<(N*4 + 255)/256, 256, 0, stream>>>(MSG, off, csr, nullptr, AGG);
    gemm_mfma<32,32,128,true,true><<<GM, 256, 0, stream>>>(AGG, b_d1Wl, zbf, b_d1Wr, d1_bl, R1bf);

    // ---- conv4 (d2): 128 -> 64 = x_rec ----
    gemm_mfma<128,0,64,false,false><<<GM, 256, 0, stream>>>(R1bf, b_d2Wr, nullptr, nullptr, d2_bl, xrec);
    gemm_mfma<128,0,128,true,true><<<GM, 256, 0, stream>>>(R1bf, b_d2Wp, nullptr, nullptr, d2_bp, Hbf);
    gemm_mfma<128,0,64,false,true><<<GM, 256, 0, stream>>>(Hbf, b_d2Wl, nullptr, nullptr, nullptr, MSG);
    pull_bf<64,1><<<(N*8 + 255)/256, 256, 0, stream>>>(MSG, off, csr, xrec, nullptr);
}